// Round 11
// baseline (208.817 us; speedup 1.0000x reference)
//
#include <hip/hip_runtime.h>

// Problem constants (from reference): N=512, OBS=32, H=128, M=128, L=3
#define NA 512
#define NOBS 32
#define NH 128

typedef const float* fp32p;
typedef __attribute__((ext_vector_type(8))) short bf16x8;
typedef __attribute__((ext_vector_type(4))) float f32x4;

// packed 2xf32 -> 2xbf16 (RNE) in one instruction (gfx950); lo -> bits[15:0]
__device__ __forceinline__ unsigned cvt_pk_bf16(float lo, float hi) {
    unsigned r;
    asm("v_cvt_pk_bf16_f32 %0, %1, %2" : "=v"(r) : "v"(lo), "v"(hi));
    return r;
}

__device__ __forceinline__ bf16x8 wfrag_f4(const float* p) {  // 16B-aligned
    float4 u = *(const float4*)p;
    float4 v = *(const float4*)(p + 4);
    union { unsigned w[4]; bf16x8 f; } r;
    r.w[0] = cvt_pk_bf16(u.x, u.y);
    r.w[1] = cvt_pk_bf16(u.z, u.w);
    r.w[2] = cvt_pk_bf16(v.x, v.y);
    r.w[3] = cvt_pk_bf16(v.z, v.w);
    return r.f;
}

__device__ __forceinline__ bf16x8 wfrag_s(const float* p) {   // unaligned-safe
    union { unsigned w[4]; bf16x8 f; } r;
    r.w[0] = cvt_pk_bf16(p[0], p[1]);
    r.w[1] = cvt_pk_bf16(p[2], p[3]);
    r.w[2] = cvt_pk_bf16(p[4], p[5]);
    r.w[3] = cvt_pk_bf16(p[6], p[7]);
    return r.f;
}

// LDS row stride (shorts). Multiple of 8 (16B alignment for ds_read_b128 --
// R7 lesson); 136 keeps b128 reads at the 8-access/bank BW floor. The ~4.3M
// SQ_LDS_BANK_CONFLICT is the b128 read-floor signature, not fixable (R8/R9).
#define HSTR 136

// ----------------------------------------- fused encoder + layer-0 ab ------
// R10 MFMA tile encoder (kept): 16 agents/block (grid 32), 8 waves x 16-col
// tiles; L1 one K=32 MFMA, L2/L3 4 MFMAs, ab 8 MFMAs.
__global__ __launch_bounds__(512) void enc_ab_kernel(
    fp32p obs, fp32p eW1, fp32p eb1, fp32p eW2, fp32p eb2, fp32p eW3, fp32p eb3,
    fp32p mW1, float* __restrict__ z, float* __restrict__ A, float* __restrict__ B) {
    const int i0 = blockIdx.x * 16;
    const int t = threadIdx.x;
    const int lane = t & 63;
    const int w = t >> 6;
    const int q = lane >> 4;
    const int c = lane & 15;
    const int q8 = q * 8;
    const int ncol = w * 16 + c;

    __shared__ short ha[16 * HSTR];   // layer activations bf16 (ping)
    __shared__ short hb[16 * HSTR];   // (pong)

    // ---- L1: h1 = relu(obs @ eW1^T + eb1), one 16x16x32 MFMA ----
    {
        const bf16x8 af = wfrag_f4(obs + (size_t)(i0 + c) * NOBS + q8);
        const bf16x8 bf = wfrag_f4(eW1 + (size_t)ncol * NOBS + q8);
        f32x4 acc = {0.f, 0.f, 0.f, 0.f};
        acc = __builtin_amdgcn_mfma_f32_16x16x32_bf16(af, bf, acc, 0, 0, 0);
        const float bn = eb1[ncol];
        #pragma unroll
        for (int r = 0; r < 4; ++r) {
            const float v = fmaxf(acc[r] + bn, 0.f);
            ha[(q * 4 + r) * HSTR + ncol] = (short)cvt_pk_bf16(v, v);
        }
    }
    __syncthreads();
    // ---- L2: h2 = relu(h1 @ eW2^T + eb2) ----
    {
        f32x4 acc = {0.f, 0.f, 0.f, 0.f};
        const short* ar = &ha[c * HSTR + q8];
        #pragma unroll
        for (int kb = 0; kb < 4; ++kb) {
            const bf16x8 a = *(const bf16x8*)(ar + kb * 32);
            const bf16x8 b = wfrag_f4(eW2 + (size_t)ncol * NH + kb * 32 + q8);
            acc = __builtin_amdgcn_mfma_f32_16x16x32_bf16(a, b, acc, 0, 0, 0);
        }
        const float bn = eb2[ncol];
        #pragma unroll
        for (int r = 0; r < 4; ++r) {
            const float v = fmaxf(acc[r] + bn, 0.f);
            hb[(q * 4 + r) * HSTR + ncol] = (short)cvt_pk_bf16(v, v);
        }
    }
    __syncthreads();
    // ---- L3: z = h2 @ eW3^T + eb3 (fp32 out + bf16 LDS for ab) ----
    {
        f32x4 acc = {0.f, 0.f, 0.f, 0.f};
        const short* ar = &hb[c * HSTR + q8];
        #pragma unroll
        for (int kb = 0; kb < 4; ++kb) {
            const bf16x8 a = *(const bf16x8*)(ar + kb * 32);
            const bf16x8 b = wfrag_f4(eW3 + (size_t)ncol * NH + kb * 32 + q8);
            acc = __builtin_amdgcn_mfma_f32_16x16x32_bf16(a, b, acc, 0, 0, 0);
        }
        const float bn = eb3[ncol];
        #pragma unroll
        for (int r = 0; r < 4; ++r) {
            const float v = acc[r] + bn;
            z[(size_t)(i0 + q * 4 + r) * NH + ncol] = v;
            ha[(q * 4 + r) * HSTR + ncol] = (short)cvt_pk_bf16(v, v);
        }
    }
    __syncthreads();
    // ---- ab layer 0: A = z@Wi^T, B = z@Wj^T (mW1 rows stride 257) ----
    {
        f32x4 aa = {0.f, 0.f, 0.f, 0.f};
        f32x4 ab = {0.f, 0.f, 0.f, 0.f};
        const short* ar = &ha[c * HSTR + q8];
        const float* wrow = mW1 + (size_t)ncol * 257;
        #pragma unroll
        for (int kb = 0; kb < 4; ++kb) {
            const bf16x8 a = *(const bf16x8*)(ar + kb * 32);
            const bf16x8 bi = wfrag_s(wrow + kb * 32 + q8);
            const bf16x8 bj = wfrag_s(wrow + 128 + kb * 32 + q8);
            aa = __builtin_amdgcn_mfma_f32_16x16x32_bf16(a, bi, aa, 0, 0, 0);
            ab = __builtin_amdgcn_mfma_f32_16x16x32_bf16(a, bj, ab, 0, 0, 0);
        }
        #pragma unroll
        for (int r = 0; r < 4; ++r) {
            A[(size_t)(i0 + q * 4 + r) * NH + ncol] = aa[r];
            B[(size_t)(i0 + q * 4 + r) * NH + ncol] = ab[r];
        }
    }
}

// -------------------------------------- fused message + update + next-ab ----
// R11: same 9 barriers, but 64-row chunks with BOTH h1 and h2 double-buffered
// (identical 79360 B LDS total) so EVERY interval carries all three streams
// {BUILD-next ∥ GEMM1-cur ∥ GEMM2-prev} instead of alternating coarse
// [BUILD∥GEMM2] / [GEMM1] intervals. T14 split: global B-loads (BLOAD->regs)
// issue at interval start; convert+LDS-store (BSTORE) after GEMM1's MFMAs
// cover the load latency. All phase bodies are the R8-proven ones
// (16x16x32, lane-pair-transpose h2 stores, HSTR=136).
__global__ __launch_bounds__(512) void msg_upd_kernel(
    const float* __restrict__ A, const float* __restrict__ B,
    fp32p pos, const float* __restrict__ zin,
    fp32p W1l, fp32p b1, fp32p W2, fp32p b2, fp32p W3, fp32p b3,
    fp32p uW1, fp32p ub1, fp32p uW2, fp32p ub2, fp32p uW3, fp32p ub3,
    fp32p msgW1n, int do_ab,
    float* __restrict__ zout, float* __restrict__ An, float* __restrict__ Bn) {
    const int i = blockIdx.x;
    const int t = threadIdx.x;
    const int lane = t & 63;
    const int w = t >> 6;
    const int q = lane >> 4;
    const int c = lane & 15;
    const int ncol = w * 16 + c;

    __shared__ short h1s[2][64 * HSTR];  // 2 x 17408 B
    __shared__ short h2s[2][64 * HSTR];  // 2 x 17408 B
    __shared__ float distrow[NA];
    __shared__ float amrow[NH];        // A_i + b1 folded
    __shared__ float wdsr[NH];
    __shared__ float xs2[2 * NH];      // [z_i | msum_i]
    __shared__ float part[4 * NH];
    __shared__ float part2[4 * NH];
    __shared__ float hx[NH], hy[NH], hz[NH];

    if (t < NH) {
        amrow[t] = A[i * NH + t] + b1[t];
        wdsr[t]  = W1l[t * 257 + 256];
        xs2[t] = zin[(size_t)i * NH + t];
    }
    {
        const float2 pi = *(const float2*)&pos[2 * i];
        const float2 pj = *(const float2*)&pos[2 * t];
        const float dx = pi.x - pj.x, dy = pi.y - pj.y;
        const float s = dx * dx + dy * dy;
        distrow[t] = (t == i) ? 0.0f : sqrtf(s);
    }

    // register-resident weight fragments (one 16-col n-tile per wave)
    bf16x8 w2f[4], w3f[4];
    {
        const float* w2r = W2 + (size_t)ncol * NH + q * 8;
        const float* w3r = W3 + (size_t)ncol * NH + q * 8;
        #pragma unroll
        for (int kb = 0; kb < 4; ++kb) {
            w2f[kb] = wfrag_f4(w2r + kb * 32);
            w3f[kb] = wfrag_f4(w3r + kb * 32);
        }
    }
    const float b2n = b2[ncol];

    const int m2 = lane * 2;
    float psum = 0.0f;

    __syncthreads();   // amrow/wdsr/distrow ready
    const float am0 = amrow[m2], am1 = amrow[m2 + 1];
    const float wd0 = wdsr[m2],  wd1 = wdsr[m2 + 1];

    float2 bv[8];      // T14 in-flight B rows (static-indexed)

#define BLOAD(k_) do {                                                       \
        const int j0_ = (k_) * 64;                                           \
        _Pragma("unroll")                                                    \
        for (int rr = 0; rr < 8; ++rr) {                                     \
            const int jg_ = j0_ + rr * 8 + w;                                \
            bv[rr] = *(const float2*)&B[(size_t)jg_ * NH + m2];              \
        }                                                                    \
    } while (0)

#define BSTORE(k_) do {                                                      \
        const int j0_ = (k_) * 64;                                           \
        short* h1d = h1s[(k_) & 1];                                          \
        _Pragma("unroll")                                                    \
        for (int rr = 0; rr < 8; ++rr) {                                     \
            const int row_ = rr * 8 + w;                                     \
            const float d_ = distrow[j0_ + row_];                            \
            const float v0_ = fmaxf(fmaf(d_, wd0, am0 + bv[rr].x), 0.0f);    \
            const float v1_ = fmaxf(fmaf(d_, wd1, am1 + bv[rr].y), 0.0f);    \
            *(unsigned*)&h1d[row_ * HSTR + m2] = cvt_pk_bf16(v0_, v1_);      \
        }                                                                    \
    } while (0)

#define GEMM1(k_) do {                                                       \
        const short* h1r = h1s[(k_) & 1];                                    \
        short* h2d = h2s[(k_) & 1];                                          \
        _Pragma("unroll")                                                    \
        for (int jt = 0; jt < 4; ++jt) {                                     \
            f32x4 acc = {0.f, 0.f, 0.f, 0.f};                                \
            const short* arow = &h1r[(jt * 16 + c) * HSTR + q * 8];          \
            _Pragma("unroll")                                                \
            for (int kb = 0; kb < 4; ++kb) {                                 \
                bf16x8 a = *(const bf16x8*)(arow + kb * 32);                 \
                acc = __builtin_amdgcn_mfma_f32_16x16x32_bf16(a, w2f[kb], acc, 0, 0, 0); \
            }                                                                \
            const int orow = jt * 16 + q * 4;                                \
            const unsigned p01 = cvt_pk_bf16(fmaxf(acc[0] + b2n, 0.0f),      \
                                             fmaxf(acc[1] + b2n, 0.0f));     \
            const unsigned p23 = cvt_pk_bf16(fmaxf(acc[2] + b2n, 0.0f),      \
                                             fmaxf(acc[3] + b2n, 0.0f));     \
            const unsigned send = (c & 1) ? p01 : p23;                       \
            const unsigned recv = __shfl_xor(send, 1, 64);                   \
            const unsigned keep = (c & 1) ? p23 : p01;                       \
            const unsigned lo = (c & 1) ? recv : keep;                       \
            const unsigned hi = (c & 1) ? keep : recv;                       \
            const unsigned d0 = (lo & 0xFFFFu) | (hi << 16);                 \
            const unsigned d1 = (lo >> 16) | (hi & 0xFFFF0000u);             \
            const int rbase = orow + ((c & 1) << 1);                         \
            const int colb = ncol & ~1;                                      \
            *(unsigned*)&h2d[(rbase + 0) * HSTR + colb] = d0;                \
            *(unsigned*)&h2d[(rbase + 1) * HSTR + colb] = d1;                \
        }                                                                    \
    } while (0)

#define GEMM2(k_) do {                                                       \
        const int j0_ = (k_) * 64;                                           \
        const short* h2r = h2s[(k_) & 1];                                    \
        _Pragma("unroll")                                                    \
        for (int jt = 0; jt < 4; ++jt) {                                     \
            f32x4 acc = {0.f, 0.f, 0.f, 0.f};                                \
            const short* arow = &h2r[(jt * 16 + c) * HSTR + q * 8];          \
            _Pragma("unroll")                                                \
            for (int kb = 0; kb < 4; ++kb) {                                 \
                bf16x8 a = *(const bf16x8*)(arow + kb * 32);                 \
                acc = __builtin_amdgcn_mfma_f32_16x16x32_bf16(a, w3f[kb], acc, 0, 0, 0); \
            }                                                                \
            _Pragma("unroll")                                                \
            for (int r = 0; r < 4; ++r) {                                    \
                const int jg_ = j0_ + jt * 16 + q * 4 + r;                   \
                if (jg_ != i) psum += acc[r];                                \
            }                                                                \
        }                                                                    \
    } while (0)

    // software pipeline: one barrier per 64-row chunk, 3 streams/interval
    BLOAD(0); BSTORE(0);
    __syncthreads();                 // h1[0] ready
    BLOAD(1); GEMM1(0); BSTORE(1);
    __syncthreads();                 // h2[0], h1[1] ready
    #pragma unroll
    for (int k = 1; k < 8; ++k) {
        if (k < 7) BLOAD(k + 1);     // issue loads early (T14)
        GEMM1(k);                    // h1[k&1] -> h2[k&1]
        if (k < 7) BSTORE(k + 1);    // loads landed under GEMM1
        GEMM2(k - 1);                // h2[(k-1)&1] -> psum
        __syncthreads();
    }
    GEMM2(7);
#undef BLOAD
#undef BSTORE
#undef GEMM1
#undef GEMM2

    // ---- msum: reduce over quads (same ncol), write straight into xs2 ----
    psum += __shfl_xor(psum, 16, 64);
    psum += __shfl_xor(psum, 32, 64);
    if (lane < 16) xs2[NH + ncol] = psum + 511.0f * b3[ncol];
    __syncthreads();

    // ---- tail: update MLP (fp32 GEMV, 4 lanes per output row) ----
    const int nn = t >> 2;   // output row 0..127
    const int ks = t & 3;    // k-segment
    // L1: K=256
    {
        const float* wr = uW1 + (size_t)nn * 256 + ks * 4;
        float p = 0.f;
        #pragma unroll
        for (int it = 0; it < 16; ++it) {
            const float4 wv = *(const float4*)(wr + it * 16);
            const float4 xv = *(const float4*)&xs2[it * 16 + ks * 4];
            p += wv.x * xv.x + wv.y * xv.y + wv.z * xv.z + wv.w * xv.w;
        }
        part[ks * NH + nn] = p;
    }
    __syncthreads();
    if (t < NH)
        hx[t] = fmaxf(ub1[t] + part[t] + part[NH + t] + part[2 * NH + t] + part[3 * NH + t], 0.f);
    __syncthreads();
    // L2: K=128
    {
        const float* wr = uW2 + (size_t)nn * NH + ks * 4;
        float p = 0.f;
        #pragma unroll
        for (int it = 0; it < 8; ++it) {
            const float4 wv = *(const float4*)(wr + it * 16);
            const float4 xv = *(const float4*)&hx[it * 16 + ks * 4];
            p += wv.x * xv.x + wv.y * xv.y + wv.z * xv.z + wv.w * xv.w;
        }
        part[ks * NH + nn] = p;
    }
    __syncthreads();
    if (t < NH)
        hy[t] = fmaxf(ub2[t] + part[t] + part[NH + t] + part[2 * NH + t] + part[3 * NH + t], 0.f);
    __syncthreads();
    // L3: K=128, no relu -> zout + hz
    {
        const float* wr = uW3 + (size_t)nn * NH + ks * 4;
        float p = 0.f;
        #pragma unroll
        for (int it = 0; it < 8; ++it) {
            const float4 wv = *(const float4*)(wr + it * 16);
            const float4 xv = *(const float4*)&hy[it * 16 + ks * 4];
            p += wv.x * xv.x + wv.y * xv.y + wv.z * xv.z + wv.w * xv.w;
        }
        part[ks * NH + nn] = p;
    }
    __syncthreads();
    if (t < NH) {
        const float v = ub3[t] + part[t] + part[NH + t] + part[2 * NH + t] + part[3 * NH + t];
        zout[(size_t)i * NH + t] = v;
        hz[t] = v;
    }
    if (!do_ab) return;
    __syncthreads();
    // ab: A = z@Wi^T, B = z@Wj^T (K=128, row stride 257 -> dword loads)
    {
        const float* pr = msgW1n + (size_t)nn * 257;
        float pa = 0.f, pb = 0.f;
        #pragma unroll
        for (int it = 0; it < 8; ++it) {
            #pragma unroll
            for (int j = 0; j < 4; ++j) {
                const int k = it * 16 + ks * 4 + j;
                const float x = hz[k];
                pa += x * pr[k];
                pb += x * pr[NH + k];
            }
        }
        part[ks * NH + nn] = pa;
        part2[ks * NH + nn] = pb;
    }
    __syncthreads();
    if (t < NH) {
        An[(size_t)i * NH + t] = part[t] + part[NH + t] + part[2 * NH + t] + part[3 * NH + t];
        Bn[(size_t)i * NH + t] = part2[t] + part2[NH + t] + part2[2 * NH + t] + part2[3 * NH + t];
    }
}

// ---------------------------------------------------------------- host ------
extern "C" void kernel_launch(void* const* d_in, const int* in_sizes, int n_in,
                              void* d_out, int out_size, void* d_ws, size_t ws_size,
                              hipStream_t stream) {
    fp32p obs   = (fp32p)d_in[0];
    fp32p pos   = (fp32p)d_in[1];
    fp32p encW1 = (fp32p)d_in[2];  fp32p encb1 = (fp32p)d_in[3];
    fp32p encW2 = (fp32p)d_in[4];  fp32p encb2 = (fp32p)d_in[5];
    fp32p encW3 = (fp32p)d_in[6];  fp32p encb3 = (fp32p)d_in[7];
    fp32p msgW1 = (fp32p)d_in[8];  fp32p msgb1 = (fp32p)d_in[9];
    fp32p msgW2 = (fp32p)d_in[10]; fp32p msgb2 = (fp32p)d_in[11];
    fp32p msgW3 = (fp32p)d_in[12]; fp32p msgb3 = (fp32p)d_in[13];
    fp32p updW1 = (fp32p)d_in[14]; fp32p updb1 = (fp32p)d_in[15];
    fp32p updW2 = (fp32p)d_in[16]; fp32p updb2 = (fp32p)d_in[17];
    fp32p updW3 = (fp32p)d_in[18]; fp32p updb3 = (fp32p)d_in[19];

    // workspace (fp32): zA | zB | A0 | B0 | A1 | B1  (1.5 MB)
    float* ws = (float*)d_ws;
    float* zA = ws;
    float* zB = zA + NA * NH;
    float* A0 = zB + NA * NH;
    float* B0 = A0 + NA * NH;
    float* A1 = B0 + NA * NH;
    float* B1 = A1 + NA * NH;

    enc_ab_kernel<<<NA / 16, 512, 0, stream>>>(obs, encW1, encb1, encW2, encb2,
                                               encW3, encb3, msgW1, zA, A0, B0);

    float* zin = zA;  float* zout = zB;
    float* Ac = A0;   float* Bc = B0;
    float* An = A1;   float* Bn = B1;
    for (int l = 0; l < 3; ++l) {
        const int do_ab = (l < 2);
        float* dst = (l == 2) ? (float*)d_out : zout;
        msg_upd_kernel<<<NA, 512, 0, stream>>>(Ac, Bc, pos, zin,
            msgW1 + (size_t)l * 128 * 257, msgb1 + l * 128,
            msgW2 + (size_t)l * 128 * 128, msgb2 + l * 128,
            msgW3 + (size_t)l * 128 * 128, msgb3 + l * 128,
            updW1 + (size_t)l * 256 * 128, updb1 + l * 128,
            updW2 + (size_t)l * 128 * 128, updb2 + l * 128,
            updW3 + (size_t)l * 128 * 128, updb3 + l * 128,
            msgW1 + (size_t)(l + 1 < 3 ? l + 1 : 0) * 128 * 257, do_ab,
            dst, An, Bn);
        float* tmp;
        tmp = zin; zin = zout; zout = tmp;
        tmp = Ac; Ac = An; An = tmp;
        tmp = Bc; Bc = Bn; Bn = tmp;
    }
}

// Round 14
// 206.786 us; speedup vs baseline: 1.0098x; 1.0098x over previous
//
#include <hip/hip_runtime.h>

// Problem constants (from reference): N=512, OBS=32, H=128, M=128, L=3
#define NA 512
#define NOBS 32
#define NH 128

typedef const float* fp32p;
typedef __attribute__((ext_vector_type(8))) short bf16x8;
typedef __attribute__((ext_vector_type(4))) float f32x4;

// packed 2xf32 -> 2xbf16 (RNE) in one instruction (gfx950); lo -> bits[15:0]
__device__ __forceinline__ unsigned cvt_pk_bf16(float lo, float hi) {
    unsigned r;
    asm("v_cvt_pk_bf16_f32 %0, %1, %2" : "=v"(r) : "v"(lo), "v"(hi));
    return r;
}

__device__ __forceinline__ bf16x8 wfrag_f4(const float* p) {  // 16B-aligned
    float4 u = *(const float4*)p;
    float4 v = *(const float4*)(p + 4);
    union { unsigned w[4]; bf16x8 f; } r;
    r.w[0] = cvt_pk_bf16(u.x, u.y);
    r.w[1] = cvt_pk_bf16(u.z, u.w);
    r.w[2] = cvt_pk_bf16(v.x, v.y);
    r.w[3] = cvt_pk_bf16(v.z, v.w);
    return r.f;
}

__device__ __forceinline__ bf16x8 wfrag_s(const float* p) {   // unaligned-safe
    union { unsigned w[4]; bf16x8 f; } r;
    r.w[0] = cvt_pk_bf16(p[0], p[1]);
    r.w[1] = cvt_pk_bf16(p[2], p[3]);
    r.w[2] = cvt_pk_bf16(p[4], p[5]);
    r.w[3] = cvt_pk_bf16(p[6], p[7]);
    return r.f;
}

// LDS row stride (shorts). Multiple of 8 (16B alignment for ds_read_b128 --
// R7 lesson); 136 keeps b128 reads at the 8-access/bank BW floor. The ~4.3M
// SQ_LDS_BANK_CONFLICT is the b128 read-floor signature, not fixable (R8/R9).
#define HSTR 136

// ----------------------------------------- fused encoder + layer-0 ab ------
// R10 MFMA tile encoder: 16 agents/block (grid 32), 8 waves x 16-col tiles;
// L1 one K=32 MFMA, L2/L3 4 MFMAs, ab 8 MFMAs.
__global__ __launch_bounds__(512) void enc_ab_kernel(
    fp32p obs, fp32p eW1, fp32p eb1, fp32p eW2, fp32p eb2, fp32p eW3, fp32p eb3,
    fp32p mW1, float* __restrict__ z, float* __restrict__ A, float* __restrict__ B) {
    const int i0 = blockIdx.x * 16;
    const int t = threadIdx.x;
    const int lane = t & 63;
    const int w = t >> 6;
    const int q = lane >> 4;
    const int c = lane & 15;
    const int q8 = q * 8;
    const int ncol = w * 16 + c;

    __shared__ short ha[16 * HSTR];   // layer activations bf16 (ping)
    __shared__ short hb[16 * HSTR];   // (pong)

    // ---- L1: h1 = relu(obs @ eW1^T + eb1), one 16x16x32 MFMA ----
    {
        const bf16x8 af = wfrag_f4(obs + (size_t)(i0 + c) * NOBS + q8);
        const bf16x8 bf = wfrag_f4(eW1 + (size_t)ncol * NOBS + q8);
        f32x4 acc = {0.f, 0.f, 0.f, 0.f};
        acc = __builtin_amdgcn_mfma_f32_16x16x32_bf16(af, bf, acc, 0, 0, 0);
        const float bn = eb1[ncol];
        #pragma unroll
        for (int r = 0; r < 4; ++r) {
            const float v = fmaxf(acc[r] + bn, 0.f);
            ha[(q * 4 + r) * HSTR + ncol] = (short)cvt_pk_bf16(v, v);
        }
    }
    __syncthreads();
    // ---- L2: h2 = relu(h1 @ eW2^T + eb2) ----
    {
        f32x4 acc = {0.f, 0.f, 0.f, 0.f};
        const short* ar = &ha[c * HSTR + q8];
        #pragma unroll
        for (int kb = 0; kb < 4; ++kb) {
            const bf16x8 a = *(const bf16x8*)(ar + kb * 32);
            const bf16x8 b = wfrag_f4(eW2 + (size_t)ncol * NH + kb * 32 + q8);
            acc = __builtin_amdgcn_mfma_f32_16x16x32_bf16(a, b, acc, 0, 0, 0);
        }
        const float bn = eb2[ncol];
        #pragma unroll
        for (int r = 0; r < 4; ++r) {
            const float v = fmaxf(acc[r] + bn, 0.f);
            hb[(q * 4 + r) * HSTR + ncol] = (short)cvt_pk_bf16(v, v);
        }
    }
    __syncthreads();
    // ---- L3: z = h2 @ eW3^T + eb3 (fp32 out + bf16 LDS for ab) ----
    {
        f32x4 acc = {0.f, 0.f, 0.f, 0.f};
        const short* ar = &hb[c * HSTR + q8];
        #pragma unroll
        for (int kb = 0; kb < 4; ++kb) {
            const bf16x8 a = *(const bf16x8*)(ar + kb * 32);
            const bf16x8 b = wfrag_f4(eW3 + (size_t)ncol * NH + kb * 32 + q8);
            acc = __builtin_amdgcn_mfma_f32_16x16x32_bf16(a, b, acc, 0, 0, 0);
        }
        const float bn = eb3[ncol];
        #pragma unroll
        for (int r = 0; r < 4; ++r) {
            const float v = acc[r] + bn;
            z[(size_t)(i0 + q * 4 + r) * NH + ncol] = v;
            ha[(q * 4 + r) * HSTR + ncol] = (short)cvt_pk_bf16(v, v);
        }
    }
    __syncthreads();
    // ---- ab layer 0: A = z@Wi^T, B = z@Wj^T (mW1 rows stride 257) ----
    {
        f32x4 aa = {0.f, 0.f, 0.f, 0.f};
        f32x4 ab = {0.f, 0.f, 0.f, 0.f};
        const short* ar = &ha[c * HSTR + q8];
        const float* wrow = mW1 + (size_t)ncol * 257;
        #pragma unroll
        for (int kb = 0; kb < 4; ++kb) {
            const bf16x8 a = *(const bf16x8*)(ar + kb * 32);
            const bf16x8 bi = wfrag_s(wrow + kb * 32 + q8);
            const bf16x8 bj = wfrag_s(wrow + 128 + kb * 32 + q8);
            aa = __builtin_amdgcn_mfma_f32_16x16x32_bf16(a, bi, aa, 0, 0, 0);
            ab = __builtin_amdgcn_mfma_f32_16x16x32_bf16(a, bj, ab, 0, 0, 0);
        }
        #pragma unroll
        for (int r = 0; r < 4; ++r) {
            A[(size_t)(i0 + q * 4 + r) * NH + ncol] = aa[r];
            B[(size_t)(i0 + q * 4 + r) * NH + ncol] = ab[r];
        }
    }
}

// -------------------------------------- fused message + update + next-ab ----
// R11 (harness-verified ~43us): 64-row chunks, h1/h2 double-buffered, 3
// streams per barrier interval {BUILD-next ∥ GEMM1-cur ∥ GEMM2-prev}, T14
// load/store split, 16x16x32 MFMA, lane-pair-transpose h2 stores, HSTR=136.
__global__ __launch_bounds__(512) void msg_upd_kernel(
    const float* __restrict__ A, const float* __restrict__ B,
    fp32p pos, const float* __restrict__ zin,
    fp32p W1l, fp32p b1, fp32p W2, fp32p b2, fp32p W3, fp32p b3,
    fp32p uW1, fp32p ub1, fp32p uW2, fp32p ub2, fp32p uW3, fp32p ub3,
    fp32p msgW1n, int do_ab,
    float* __restrict__ zout, float* __restrict__ An, float* __restrict__ Bn) {
    const int i = blockIdx.x;
    const int t = threadIdx.x;
    const int lane = t & 63;
    const int w = t >> 6;
    const int q = lane >> 4;
    const int c = lane & 15;
    const int ncol = w * 16 + c;

    __shared__ short h1s[2][64 * HSTR];  // 2 x 17408 B
    __shared__ short h2s[2][64 * HSTR];  // 2 x 17408 B
    __shared__ float distrow[NA];
    __shared__ float amrow[NH];        // A_i + b1 folded
    __shared__ float wdsr[NH];
    __shared__ float xs2[2 * NH];      // [z_i | msum_i]
    __shared__ float part[4 * NH];
    __shared__ float part2[4 * NH];
    __shared__ float hx[NH], hy[NH], hz[NH];

    if (t < NH) {
        amrow[t] = A[i * NH + t] + b1[t];
        wdsr[t]  = W1l[t * 257 + 256];
        xs2[t] = zin[(size_t)i * NH + t];
    }
    {
        const float2 pi = *(const float2*)&pos[2 * i];
        const float2 pj = *(const float2*)&pos[2 * t];
        const float dx = pi.x - pj.x, dy = pi.y - pj.y;
        const float s = dx * dx + dy * dy;
        distrow[t] = (t == i) ? 0.0f : sqrtf(s);
    }

    // register-resident weight fragments (one 16-col n-tile per wave)
    bf16x8 w2f[4], w3f[4];
    {
        const float* w2r = W2 + (size_t)ncol * NH + q * 8;
        const float* w3r = W3 + (size_t)ncol * NH + q * 8;
        #pragma unroll
        for (int kb = 0; kb < 4; ++kb) {
            w2f[kb] = wfrag_f4(w2r + kb * 32);
            w3f[kb] = wfrag_f4(w3r + kb * 32);
        }
    }
    const float b2n = b2[ncol];

    const int m2 = lane * 2;
    float psum = 0.0f;

    __syncthreads();   // amrow/wdsr/distrow ready
    const float am0 = amrow[m2], am1 = amrow[m2 + 1];
    const float wd0 = wdsr[m2],  wd1 = wdsr[m2 + 1];

    float2 bv[8];      // T14 in-flight B rows (static-indexed)

#define BLOAD(k_) do {                                                       \
        const int j0_ = (k_) * 64;                                           \
        _Pragma("unroll")                                                    \
        for (int rr = 0; rr < 8; ++rr) {                                     \
            const int jg_ = j0_ + rr * 8 + w;                                \
            bv[rr] = *(const float2*)&B[(size_t)jg_ * NH + m2];              \
        }                                                                    \
    } while (0)

#define BSTORE(k_) do {                                                      \
        const int j0_ = (k_) * 64;                                           \
        short* h1d = h1s[(k_) & 1];                                          \
        _Pragma("unroll")                                                    \
        for (int rr = 0; rr < 8; ++rr) {                                     \
            const int row_ = rr * 8 + w;                                     \
            const float d_ = distrow[j0_ + row_];                            \
            const float v0_ = fmaxf(fmaf(d_, wd0, am0 + bv[rr].x), 0.0f);    \
            const float v1_ = fmaxf(fmaf(d_, wd1, am1 + bv[rr].y), 0.0f);    \
            *(unsigned*)&h1d[row_ * HSTR + m2] = cvt_pk_bf16(v0_, v1_);      \
        }                                                                    \
    } while (0)

#define GEMM1(k_) do {                                                       \
        const short* h1r = h1s[(k_) & 1];                                    \
        short* h2d = h2s[(k_) & 1];                                          \
        _Pragma("unroll")                                                    \
        for (int jt = 0; jt < 4; ++jt) {                                     \
            f32x4 acc = {0.f, 0.f, 0.f, 0.f};                                \
            const short* arow = &h1r[(jt * 16 + c) * HSTR + q * 8];          \
            _Pragma("unroll")                                                \
            for (int kb = 0; kb < 4; ++kb) {                                 \
                bf16x8 a = *(const bf16x8*)(arow + kb * 32);                 \
                acc = __builtin_amdgcn_mfma_f32_16x16x32_bf16(a, w2f[kb], acc, 0, 0, 0); \
            }                                                                \
            const int orow = jt * 16 + q * 4;                                \
            const unsigned p01 = cvt_pk_bf16(fmaxf(acc[0] + b2n, 0.0f),      \
                                             fmaxf(acc[1] + b2n, 0.0f));     \
            const unsigned p23 = cvt_pk_bf16(fmaxf(acc[2] + b2n, 0.0f),      \
                                             fmaxf(acc[3] + b2n, 0.0f));     \
            const unsigned send = (c & 1) ? p01 : p23;                       \
            const unsigned recv = __shfl_xor(send, 1, 64);                   \
            const unsigned keep = (c & 1) ? p23 : p01;                       \
            const unsigned lo = (c & 1) ? recv : keep;                       \
            const unsigned hi = (c & 1) ? keep : recv;                       \
            const unsigned d0 = (lo & 0xFFFFu) | (hi << 16);                 \
            const unsigned d1 = (lo >> 16) | (hi & 0xFFFF0000u);             \
            const int rbase = orow + ((c & 1) << 1);                         \
            const int colb = ncol & ~1;                                      \
            *(unsigned*)&h2d[(rbase + 0) * HSTR + colb] = d0;                \
            *(unsigned*)&h2d[(rbase + 1) * HSTR + colb] = d1;                \
        }                                                                    \
    } while (0)

#define GEMM2(k_) do {                                                       \
        const int j0_ = (k_) * 64;                                           \
        const short* h2r = h2s[(k_) & 1];                                    \
        _Pragma("unroll")                                                    \
        for (int jt = 0; jt < 4; ++jt) {                                     \
            f32x4 acc = {0.f, 0.f, 0.f, 0.f};                                \
            const short* arow = &h2r[(jt * 16 + c) * HSTR + q * 8];          \
            _Pragma("unroll")                                                \
            for (int kb = 0; kb < 4; ++kb) {                                 \
                bf16x8 a = *(const bf16x8*)(arow + kb * 32);                 \
                acc = __builtin_amdgcn_mfma_f32_16x16x32_bf16(a, w3f[kb], acc, 0, 0, 0); \
            }                                                                \
            _Pragma("unroll")                                                \
            for (int r = 0; r < 4; ++r) {                                    \
                const int jg_ = j0_ + jt * 16 + q * 4 + r;                   \
                if (jg_ != i) psum += acc[r];                                \
            }                                                                \
        }                                                                    \
    } while (0)

    // software pipeline: one barrier per 64-row chunk, 3 streams/interval
    BLOAD(0); BSTORE(0);
    __syncthreads();                 // h1[0] ready
    BLOAD(1); GEMM1(0); BSTORE(1);
    __syncthreads();                 // h2[0], h1[1] ready
    #pragma unroll
    for (int k = 1; k < 8; ++k) {
        if (k < 7) BLOAD(k + 1);     // issue loads early (T14)
        GEMM1(k);                    // h1[k&1] -> h2[k&1]
        if (k < 7) BSTORE(k + 1);    // loads landed under GEMM1
        GEMM2(k - 1);                // h2[(k-1)&1] -> psum
        __syncthreads();
    }
    GEMM2(7);
#undef BLOAD
#undef BSTORE
#undef GEMM1
#undef GEMM2

    // ---- msum: reduce over quads (same ncol), write straight into xs2 ----
    psum += __shfl_xor(psum, 16, 64);
    psum += __shfl_xor(psum, 32, 64);
    if (lane < 16) xs2[NH + ncol] = psum + 511.0f * b3[ncol];
    __syncthreads();

    // ---- tail: update MLP (fp32 GEMV, 4 lanes per output row) ----
    const int nn = t >> 2;   // output row 0..127
    const int ks = t & 3;    // k-segment
    // L1: K=256
    {
        const float* wr = uW1 + (size_t)nn * 256 + ks * 4;
        float p = 0.f;
        #pragma unroll
        for (int it = 0; it < 16; ++it) {
            const float4 wv = *(const float4*)(wr + it * 16);
            const float4 xv = *(const float4*)&xs2[it * 16 + ks * 4];
            p += wv.x * xv.x + wv.y * xv.y + wv.z * xv.z + wv.w * xv.w;
        }
        part[ks * NH + nn] = p;
    }
    __syncthreads();
    if (t < NH)
        hx[t] = fmaxf(ub1[t] + part[t] + part[NH + t] + part[2 * NH + t] + part[3 * NH + t], 0.f);
    __syncthreads();
    // L2: K=128
    {
        const float* wr = uW2 + (size_t)nn * NH + ks * 4;
        float p = 0.f;
        #pragma unroll
        for (int it = 0; it < 8; ++it) {
            const float4 wv = *(const float4*)(wr + it * 16);
            const float4 xv = *(const float4*)&hx[it * 16 + ks * 4];
            p += wv.x * xv.x + wv.y * xv.y + wv.z * xv.z + wv.w * xv.w;
        }
        part[ks * NH + nn] = p;
    }
    __syncthreads();
    if (t < NH)
        hy[t] = fmaxf(ub2[t] + part[t] + part[NH + t] + part[2 * NH + t] + part[3 * NH + t], 0.f);
    __syncthreads();
    // L3: K=128, no relu -> zout + hz
    {
        const float* wr = uW3 + (size_t)nn * NH + ks * 4;
        float p = 0.f;
        #pragma unroll
        for (int it = 0; it < 8; ++it) {
            const float4 wv = *(const float4*)(wr + it * 16);
            const float4 xv = *(const float4*)&hy[it * 16 + ks * 4];
            p += wv.x * xv.x + wv.y * xv.y + wv.z * xv.z + wv.w * xv.w;
        }
        part[ks * NH + nn] = p;
    }
    __syncthreads();
    if (t < NH) {
        const float v = ub3[t] + part[t] + part[NH + t] + part[2 * NH + t] + part[3 * NH + t];
        zout[(size_t)i * NH + t] = v;
        hz[t] = v;
    }
    if (!do_ab) return;
    __syncthreads();
    // ab: A = z@Wi^T, B = z@Wj^T (K=128, row stride 257 -> dword loads)
    {
        const float* pr = msgW1n + (size_t)nn * 257;
        float pa = 0.f, pb = 0.f;
        #pragma unroll
        for (int it = 0; it < 8; ++it) {
            #pragma unroll
            for (int j = 0; j < 4; ++j) {
                const int k = it * 16 + ks * 4 + j;
                const float x = hz[k];
                pa += x * pr[k];
                pb += x * pr[NH + k];
            }
        }
        part[ks * NH + nn] = pa;
        part2[ks * NH + nn] = pb;
    }
    __syncthreads();
    if (t < NH) {
        An[(size_t)i * NH + t] = part[t] + part[NH + t] + part[2 * NH + t] + part[3 * NH + t];
        Bn[(size_t)i * NH + t] = part2[t] + part2[NH + t] + part2[2 * NH + t] + part2[3 * NH + t];
    }
}

// ---------------------------------------------------------------- host ------
extern "C" void kernel_launch(void* const* d_in, const int* in_sizes, int n_in,
                              void* d_out, int out_size, void* d_ws, size_t ws_size,
                              hipStream_t stream) {
    fp32p obs   = (fp32p)d_in[0];
    fp32p pos   = (fp32p)d_in[1];
    fp32p encW1 = (fp32p)d_in[2];  fp32p encb1 = (fp32p)d_in[3];
    fp32p encW2 = (fp32p)d_in[4];  fp32p encb2 = (fp32p)d_in[5];
    fp32p encW3 = (fp32p)d_in[6];  fp32p encb3 = (fp32p)d_in[7];
    fp32p msgW1 = (fp32p)d_in[8];  fp32p msgb1 = (fp32p)d_in[9];
    fp32p msgW2 = (fp32p)d_in[10]; fp32p msgb2 = (fp32p)d_in[11];
    fp32p msgW3 = (fp32p)d_in[12]; fp32p msgb3 = (fp32p)d_in[13];
    fp32p updW1 = (fp32p)d_in[14]; fp32p updb1 = (fp32p)d_in[15];
    fp32p updW2 = (fp32p)d_in[16]; fp32p updb2 = (fp32p)d_in[17];
    fp32p updW3 = (fp32p)d_in[18]; fp32p updb3 = (fp32p)d_in[19];

    // workspace (fp32): zA | zB | A0 | B0 | A1 | B1  (1.5 MB)
    float* ws = (float*)d_ws;
    float* zA = ws;
    float* zB = zA + NA * NH;
    float* A0 = zB + NA * NH;
    float* B0 = A0 + NA * NH;
    float* A1 = B0 + NA * NH;
    float* B1 = A1 + NA * NH;

    enc_ab_kernel<<<NA / 16, 512, 0, stream>>>(obs, encW1, encb1, encW2, encb2,
                                               encW3, encb3, msgW1, zA, A0, B0);

    float* zin = zA;  float* zout = zB;
    float* Ac = A0;   float* Bc = B0;
    float* An = A1;   float* Bn = B1;
    for (int l = 0; l < 3; ++l) {
        const int do_ab = (l < 2);
        float* dst = (l == 2) ? (float*)d_out : zout;
        msg_upd_kernel<<<NA, 512, 0, stream>>>(Ac, Bc, pos, zin,
            msgW1 + (size_t)l * 128 * 257, msgb1 + l * 128,
            msgW2 + (size_t)l * 128 * 128, msgb2 + l * 128,
            msgW3 + (size_t)l * 128 * 128, msgb3 + l * 128,
            updW1 + (size_t)l * 256 * 128, updb1 + l * 128,
            updW2 + (size_t)l * 128 * 128, updb2 + l * 128,
            updW3 + (size_t)l * 128 * 128, updb3 + l * 128,
            msgW1 + (size_t)(l + 1 < 3 ? l + 1 : 0) * 128 * 257, do_ab,
            dst, An, Bn);
        float* tmp;
        tmp = zin; zin = zout; zout = tmp;
        tmp = Ac; Ac = An; An = tmp;
        tmp = Bc; Bc = Bn; Bn = tmp;
    }
}